// Round 1
// baseline (144.256 us; speedup 1.0000x reference)
//
#include <hip/hip_runtime.h>

#define BN 512
#define DIM 128
#define TMARGIN 0.3f

// ---------------------------------------------------------------------------
// Kernel 1: pairwise distance matrix. One block per anchor row i.
// dist[i][j] = sqrt(max(||e_i||^2 + ||e_j||^2 - 2 e_i.e_j, 1e-12))
// ---------------------------------------------------------------------------
__global__ __launch_bounds__(256) void dist_kernel(const float* __restrict__ emb,
                                                   float* __restrict__ dist) {
    const int i = blockIdx.x;
    __shared__ float row[DIM];
    const int tid = threadIdx.x;
    if (tid < DIM) row[tid] = emb[i * DIM + tid];
    __syncthreads();

    // squared norm of anchor row (redundant per-thread, 128 LDS reads — cheap)
    float sqi = 0.f;
#pragma unroll
    for (int d = 0; d < DIM; ++d) sqi += row[d] * row[d];

    for (int j = tid; j < BN; j += 256) {
        const float4* e4 = reinterpret_cast<const float4*>(emb + (size_t)j * DIM);
        float dot = 0.f, sqj = 0.f;
#pragma unroll
        for (int q = 0; q < DIM / 4; ++q) {
            float4 v = e4[q];
            dot += row[4 * q + 0] * v.x + row[4 * q + 1] * v.y +
                   row[4 * q + 2] * v.z + row[4 * q + 3] * v.w;
            sqj += v.x * v.x + v.y * v.y + v.z * v.z + v.w * v.w;
        }
        float d2 = sqi + sqj - 2.f * dot;
        d2 = fmaxf(d2, 1e-12f);
        dist[i * BN + j] = sqrtf(d2);
    }
}

// ---------------------------------------------------------------------------
// Kernel 2: per-anchor triplet accumulation. One block per anchor i.
// For each positive j: d_neg = semi-hard max if any, else min_neg(i).
// Accumulate sum(relu(d_ap - d_neg + margin)) and count over valid pairs.
// ---------------------------------------------------------------------------
__global__ __launch_bounds__(256) void triplet_kernel(const float* __restrict__ dist,
                                                      const int* __restrict__ labels,
                                                      float* __restrict__ accum) {
    const int i = blockIdx.x;
    __shared__ float drow[BN];
    __shared__ int   lab[BN];
    __shared__ float red_f[256];
    __shared__ int   red_i[256];
    const int tid = threadIdx.x;

    for (int j = tid; j < BN; j += 256) {
        drow[j] = dist[i * BN + j];
        lab[j]  = labels[j];
    }
    __syncthreads();
    const int li = lab[i];

    // min over negatives of row i, plus has_neg
    float mn = 1e30f;
    int   hn = 0;
    for (int j = tid; j < BN; j += 256) {
        if (lab[j] != li) { hn = 1; mn = fminf(mn, drow[j]); }
    }
    red_f[tid] = mn;
    red_i[tid] = hn;
    __syncthreads();
    for (int s = 128; s > 0; s >>= 1) {
        if (tid < s) {
            red_f[tid] = fminf(red_f[tid], red_f[tid + s]);
            red_i[tid] |= red_i[tid + s];
        }
        __syncthreads();
    }
    const float min_neg = red_f[0];
    const int   has_neg = red_i[0];
    __syncthreads();  // red arrays reused below

    float local_sum = 0.f;
    int   local_cnt = 0;
    if (has_neg) {
        for (int j = tid; j < BN; j += 256) {
            if (lab[j] == li && j != i) {
                const float dap = drow[j];
                const float hi  = dap + TMARGIN;
                float smax = -1e30f;
                int   hs   = 0;
                for (int k = 0; k < BN; ++k) {
                    const float dan = drow[k];
                    if (lab[k] != li && dan > dap && dan < hi) {
                        hs = 1;
                        smax = fmaxf(smax, dan);
                    }
                }
                const float dneg = hs ? smax : min_neg;
                const float pp   = dap - dneg + TMARGIN;
                local_sum += fmaxf(pp, 0.f);
                local_cnt += 1;
            }
        }
    }
    red_f[tid] = local_sum;
    red_i[tid] = local_cnt;
    __syncthreads();
    for (int s = 128; s > 0; s >>= 1) {
        if (tid < s) {
            red_f[tid] += red_f[tid + s];
            red_i[tid] += red_i[tid + s];
        }
        __syncthreads();
    }
    if (tid == 0) {
        atomicAdd(&accum[0], red_f[0]);
        atomicAdd(&accum[1], (float)red_i[0]);
    }
}

// ---------------------------------------------------------------------------
// Kernel 3: finalize scalar
// ---------------------------------------------------------------------------
__global__ void finalize_kernel(const float* __restrict__ accum,
                                float* __restrict__ out) {
    const float total = accum[0];
    const float cnt   = accum[1];
    out[0] = (cnt > 0.f) ? (total / fmaxf(cnt, 1.f)) : 0.f;
}

extern "C" void kernel_launch(void* const* d_in, const int* in_sizes, int n_in,
                              void* d_out, int out_size, void* d_ws, size_t ws_size,
                              hipStream_t stream) {
    const float* emb    = (const float*)d_in[0];
    const int*   labels = (const int*)d_in[1];
    float*       out    = (float*)d_out;

    float* dist  = (float*)d_ws;            // BN*BN floats = 1 MB
    float* accum = dist + (size_t)BN * BN;  // 2 floats (sum, count)

    hipMemsetAsync(accum, 0, 2 * sizeof(float), stream);
    dist_kernel<<<BN, 256, 0, stream>>>(emb, dist);
    triplet_kernel<<<BN, 256, 0, stream>>>(dist, labels, accum);
    finalize_kernel<<<1, 1, 0, stream>>>(accum, out);
}

// Round 2
// 93.243 us; speedup vs baseline: 1.5471x; 1.5471x over previous
//
#include <hip/hip_runtime.h>

#define BN 512
#define DIM 128
#define TMARGIN 0.3f
#define NT 256
#define NW 4  // waves per block (NT/64)

// One block per anchor i. Computes dist row i from emb (L2-resident),
// builds positives list, per-wave cooperative semi-hard max scan,
// accumulates loss; last block (ticket) finalizes the scalar output.
__global__ __launch_bounds__(NT) void fused_triplet_kernel(
        const float* __restrict__ emb,
        const int* __restrict__ labels,
        float* __restrict__ accum,   // [0]=sum, [1]=cnt, [2]=ticket(int)
        float* __restrict__ out) {
    const int i    = blockIdx.x;
    const int tid  = threadIdx.x;
    const int lane = tid & 63;
    const int wave = tid >> 6;

    __shared__ float row[DIM];
    __shared__ float drow[BN];
    __shared__ int   lab[BN];
    __shared__ int   pos_idx[BN];
    __shared__ int   npos_s;
    __shared__ float wsum[NW];
    __shared__ int   wcnt[NW];

    if (tid < DIM) row[tid] = emb[i * DIM + tid];
    if (tid == 0)  npos_s = 0;
    for (int j = tid; j < BN; j += NT) lab[j] = labels[j];
    __syncthreads();

    const int li = lab[i];

    // anchor squared norm (LDS reads, cheap)
    float sqi = 0.f;
#pragma unroll
    for (int d = 0; d < DIM; ++d) sqi += row[d] * row[d];

    // dist row + positives list
    for (int j = tid; j < BN; j += NT) {
        const float4* e4 = reinterpret_cast<const float4*>(emb + (size_t)j * DIM);
        float dot = 0.f, sqj = 0.f;
#pragma unroll
        for (int q = 0; q < DIM / 4; ++q) {
            float4 v = e4[q];
            dot += row[4*q+0]*v.x + row[4*q+1]*v.y + row[4*q+2]*v.z + row[4*q+3]*v.w;
            sqj += v.x*v.x + v.y*v.y + v.z*v.z + v.w*v.w;
        }
        float d2 = sqi + sqj - 2.f * dot;
        drow[j] = sqrtf(fmaxf(d2, 1e-12f));
        if (lab[j] == li && j != i) {
            int p = atomicAdd(&npos_s, 1);
            pos_idx[p] = j;
        }
    }
    __syncthreads();

    // per-wave min over negatives + has_neg (full row per wave, barrier-free)
    float mn = 1e30f;
    int   hn = 0;
    for (int k = lane; k < BN; k += 64) {
        if (lab[k] != li) { hn = 1; mn = fminf(mn, drow[k]); }
    }
#pragma unroll
    for (int off = 32; off > 0; off >>= 1) {
        mn = fminf(mn, __shfl_down(mn, off));
        hn |= __shfl_down(hn, off);
    }
    mn = __shfl(mn, 0);
    hn = __shfl(hn, 0);

    // positives distributed round-robin over waves; each wave scans all k
    float lsum = 0.f;
    int   lcnt = 0;
    const int npos = npos_s;
    if (hn) {
        for (int p = wave; p < npos; p += NW) {
            const float dap = drow[pos_idx[p]];
            const float hi  = dap + TMARGIN;
            float smax = -1e30f;
            for (int k = lane; k < BN; k += 64) {
                const float dan = drow[k];
                if (lab[k] != li && dan > dap && dan < hi)
                    smax = fmaxf(smax, dan);
            }
#pragma unroll
            for (int off = 32; off > 0; off >>= 1)
                smax = fmaxf(smax, __shfl_down(smax, off));
            if (lane == 0) {
                const float dneg = (smax > -1e29f) ? smax : mn;
                lsum += fmaxf(dap - dneg + TMARGIN, 0.f);
                lcnt += 1;
            }
        }
    }
    if (lane == 0) { wsum[wave] = lsum; wcnt[wave] = lcnt; }
    __syncthreads();

    if (tid == 0) {
        float s = 0.f;
        int   c = 0;
#pragma unroll
        for (int w = 0; w < NW; ++w) { s += wsum[w]; c += wcnt[w]; }
        atomicAdd(&accum[0], s);
        atomicAdd(&accum[1], (float)c);
        __threadfence();
        int t = atomicAdd((int*)(accum + 2), 1);
        if (t == (int)gridDim.x - 1) {
            // last block: read via device-scope RMW (guaranteed fresh)
            const float total = atomicAdd(&accum[0], 0.f);
            const float cnt   = atomicAdd(&accum[1], 0.f);
            out[0] = (cnt > 0.f) ? (total / fmaxf(cnt, 1.f)) : 0.f;
        }
    }
}

extern "C" void kernel_launch(void* const* d_in, const int* in_sizes, int n_in,
                              void* d_out, int out_size, void* d_ws, size_t ws_size,
                              hipStream_t stream) {
    const float* emb    = (const float*)d_in[0];
    const int*   labels = (const int*)d_in[1];
    float*       out    = (float*)d_out;
    float*       accum  = (float*)d_ws;  // 3 words: sum, cnt, ticket

    hipMemsetAsync(accum, 0, 3 * sizeof(float), stream);
    fused_triplet_kernel<<<BN, NT, 0, stream>>>(emb, labels, accum, out);
}

// Round 3
// 81.994 us; speedup vs baseline: 1.7593x; 1.1372x over previous
//
#include <hip/hip_runtime.h>

#define BN 512
#define DIM 128
#define TMARGIN 0.3f
#define TS 32      // GEMM tile edge
#define LDP 132    // padded LDS leading dim (floats); 132*4 B keeps 16B alignment
#define NT 256
#define NW 4       // waves per block

// ---------------------------------------------------------------------------
// K1: dist[i][j] = sqrt(max(sq_i + sq_j - 2 e_i.e_j, 1e-12)) via tiled GEMM.
// 256 blocks, one 32x32 tile each. Block 0 also zeroes the accumulators
// (replaces the memset dispatch; stream order makes this visible to K2).
// ---------------------------------------------------------------------------
__global__ __launch_bounds__(NT) void dist_gemm_kernel(
        const float* __restrict__ emb,
        float* __restrict__ dist,
        float* __restrict__ accum) {
    const int tile = blockIdx.x;        // 0..255
    const int tr0  = (tile >> 4) * TS;  // global row base
    const int tc0  = (tile & 15) * TS;  // global col base
    const int tid  = threadIdx.x;

    __shared__ float As[TS][LDP];
    __shared__ float Bs[TS][LDP];
    __shared__ float sqa[TS], sqb[TS];

    if (tile == 0 && tid == 0) {
        accum[0] = 0.f; accum[1] = 0.f; ((int*)accum)[2] = 0;
    }

    // Coalesced staging: 32 rows x 128 floats = 1024 float4 per tile.
    const float4* emb4 = (const float4*)emb;
#pragma unroll
    for (int q = 0; q < 4; ++q) {
        const int idx = q * NT + tid;          // 0..1023
        const int r   = idx >> 5;              // row within tile
        const int c4  = idx & 31;              // float4 col
        float4 va = emb4[(size_t)(tr0 + r) * 32 + c4];
        *(float4*)&As[r][c4 * 4] = va;
        float4 vb = emb4[(size_t)(tc0 + r) * 32 + c4];
        *(float4*)&Bs[r][c4 * 4] = vb;
    }
    __syncthreads();

    // Row squared norms from staged tiles (threads 0-31: A, 64-95: B).
    if (tid < TS) {
        float s = 0.f;
#pragma unroll
        for (int k = 0; k < DIM; k += 4) {
            float4 v = *(float4*)&As[tid][k];
            s += v.x * v.x + v.y * v.y + v.z * v.z + v.w * v.w;
        }
        sqa[tid] = s;
    } else if (tid >= 64 && tid < 64 + TS) {
        const int r = tid - 64;
        float s = 0.f;
#pragma unroll
        for (int k = 0; k < DIM; k += 4) {
            float4 v = *(float4*)&Bs[r][k];
            s += v.x * v.x + v.y * v.y + v.z * v.z + v.w * v.w;
        }
        sqb[r] = s;
    }
    __syncthreads();

    // 2x2 micro-tile per thread.
    const int tr = (tid >> 4) * 2;
    const int tc = (tid & 15) * 2;
    float a00 = 0.f, a01 = 0.f, a10 = 0.f, a11 = 0.f;
#pragma unroll
    for (int k = 0; k < DIM; k += 4) {
        float4 fa0 = *(float4*)&As[tr][k];
        float4 fa1 = *(float4*)&As[tr + 1][k];
        float4 fb0 = *(float4*)&Bs[tc][k];
        float4 fb1 = *(float4*)&Bs[tc + 1][k];
        a00 += fa0.x*fb0.x + fa0.y*fb0.y + fa0.z*fb0.z + fa0.w*fb0.w;
        a01 += fa0.x*fb1.x + fa0.y*fb1.y + fa0.z*fb1.z + fa0.w*fb1.w;
        a10 += fa1.x*fb0.x + fa1.y*fb0.y + fa1.z*fb0.z + fa1.w*fb0.w;
        a11 += fa1.x*fb1.x + fa1.y*fb1.y + fa1.z*fb1.z + fa1.w*fb1.w;
    }

    float acc[2][2] = {{a00, a01}, {a10, a11}};
#pragma unroll
    for (int rr = 0; rr < 2; ++rr)
#pragma unroll
        for (int cc = 0; cc < 2; ++cc) {
            const float d2 = sqa[tr + rr] + sqb[tc + cc] - 2.f * acc[rr][cc];
            dist[(size_t)(tr0 + tr + rr) * BN + (tc0 + tc + cc)] =
                sqrtf(fmaxf(d2, 1e-12f));
        }
}

// ---------------------------------------------------------------------------
// K2: per-anchor triplet accumulation + ticketed finalize. One block per i.
// ---------------------------------------------------------------------------
__global__ __launch_bounds__(NT) void triplet_kernel(
        const float* __restrict__ dist,
        const int* __restrict__ labels,
        float* __restrict__ accum,   // [0]=sum, [1]=cnt, [2]=ticket(int)
        float* __restrict__ out) {
    const int i    = blockIdx.x;
    const int tid  = threadIdx.x;
    const int lane = tid & 63;
    const int wave = tid >> 6;

    __shared__ float drow[BN];
    __shared__ int   lab[BN];
    __shared__ int   pos_idx[BN];
    __shared__ int   npos_s;
    __shared__ float wsum[NW];
    __shared__ int   wcnt[NW];

    // Coalesced stage of dist row i (2 KB) + labels.
    {
        float2 v = *(const float2*)&dist[(size_t)i * BN + 2 * tid];
        drow[2 * tid]     = v.x;
        drow[2 * tid + 1] = v.y;
    }
    lab[tid]       = labels[tid];
    lab[tid + 256] = labels[tid + 256];
    if (tid == 0) npos_s = 0;
    __syncthreads();

    const int li = lab[i];

    // Positives list (LDS atomic append).
    for (int j = tid; j < BN; j += NT) {
        if (lab[j] == li && j != i) {
            int p = atomicAdd(&npos_s, 1);
            pos_idx[p] = j;
        }
    }

    // Per-wave min over negatives + has_neg (barrier-free, redundant per wave).
    float mn = 1e30f;
    int   hn = 0;
    for (int k = lane; k < BN; k += 64) {
        if (lab[k] != li) { hn = 1; mn = fminf(mn, drow[k]); }
    }
#pragma unroll
    for (int off = 32; off > 0; off >>= 1) {
        mn = fminf(mn, __shfl_down(mn, off));
        hn |= __shfl_down(hn, off);
    }
    mn = __shfl(mn, 0);
    hn = __shfl(hn, 0);
    __syncthreads();  // npos_s / pos_idx ready

    // Positives round-robin over waves; wave-cooperative semi-hard max scan.
    float lsum = 0.f;
    int   lcnt = 0;
    const int npos = npos_s;
    if (hn) {
        for (int p = wave; p < npos; p += NW) {
            const float dap = drow[pos_idx[p]];
            const float hi  = dap + TMARGIN;
            float smax = -1e30f;
            for (int k = lane; k < BN; k += 64) {
                const float dan = drow[k];
                if (lab[k] != li && dan > dap && dan < hi)
                    smax = fmaxf(smax, dan);
            }
#pragma unroll
            for (int off = 32; off > 0; off >>= 1)
                smax = fmaxf(smax, __shfl_down(smax, off));
            if (lane == 0) {
                const float dneg = (smax > -1e29f) ? smax : mn;
                lsum += fmaxf(dap - dneg + TMARGIN, 0.f);
                lcnt += 1;
            }
        }
    }
    if (lane == 0) { wsum[wave] = lsum; wcnt[wave] = lcnt; }
    __syncthreads();

    if (tid == 0) {
        float s = 0.f;
        int   c = 0;
#pragma unroll
        for (int w = 0; w < NW; ++w) { s += wsum[w]; c += wcnt[w]; }
        atomicAdd(&accum[0], s);
        atomicAdd(&accum[1], (float)c);
        __threadfence();
        int t = atomicAdd((int*)(accum + 2), 1);
        if (t == (int)gridDim.x - 1) {
            const float total = atomicAdd(&accum[0], 0.f);
            const float cnt   = atomicAdd(&accum[1], 0.f);
            out[0] = (cnt > 0.f) ? (total / fmaxf(cnt, 1.f)) : 0.f;
        }
    }
}

extern "C" void kernel_launch(void* const* d_in, const int* in_sizes, int n_in,
                              void* d_out, int out_size, void* d_ws, size_t ws_size,
                              hipStream_t stream) {
    const float* emb    = (const float*)d_in[0];
    const int*   labels = (const int*)d_in[1];
    float*       out    = (float*)d_out;

    float* dist  = (float*)d_ws;            // 512*512 floats = 1 MB
    float* accum = dist + (size_t)BN * BN;  // 3 words: sum, cnt, ticket

    dist_gemm_kernel<<<256, NT, 0, stream>>>(emb, dist, accum);
    triplet_kernel<<<BN, NT, 0, stream>>>(dist, labels, accum, out);
}

// Round 4
// 80.590 us; speedup vs baseline: 1.7900x; 1.0174x over previous
//
#include <hip/hip_runtime.h>

#define BN 512
#define DIM 128
#define TMARGIN 0.3f
#define NT 256
#define NW 4   // waves per block

#define FMA4(ACC, U, V)                                                \
    ACC.x += U.x * V.x; ACC.y += U.y * V.y;                            \
    ACC.z += U.z * V.z; ACC.w += U.w * V.w;

__device__ __forceinline__ float hsum4(float4 v) {
    return (v.x + v.y) + (v.z + v.w);
}

// ---------------------------------------------------------------------------
// K1: partial squared distances, K-split over 2 blocks per 32x32 tile.
// Block b: tile = b>>1, half h = b&1 covers dims [h*64, h*64+64).
// Writes d2part[h][i][j] = sq_h(i) + sq_h(j) - 2*dot_h(i,j)  (plain stores).
// Full d2 = d2part[0] + d2part[1]; K2 adds + sqrts.
// Grid 512 = 2 blocks/CU -> 8 waves/CU for latency hiding.
// ---------------------------------------------------------------------------
__global__ __launch_bounds__(NT) void dist2_gemm_kernel(
        const float* __restrict__ emb,
        float* __restrict__ d2part,     // 2 * BN * BN floats
        float* __restrict__ accum) {
    const int b    = blockIdx.x;
    const int tile = b >> 1;
    const int h    = b & 1;
    const int tr0  = (tile >> 4) * 32;
    const int tc0  = (tile & 15) * 32;
    const int tid  = threadIdx.x;

    // Fragment-blocked LDS: Af[k4][r] = float4 of dims (h*64 + 4*k4 ..+3) of
    // row (tr0+r). Pad 33 spreads staging-write banks; fragment reads are
    // conflict-free (A: 4 rows + broadcast; B: 16 rows -> 2-way, free).
    __shared__ float4 Af[16][33];
    __shared__ float4 Bf[16][33];

    if (b == 0 && tid == 0) {
        accum[0] = 0.f; accum[1] = 0.f; ((int*)accum)[2] = 0;
    }

    const float4* emb4 = (const float4*)emb;
    const int h16 = h * 16;
#pragma unroll
    for (int s = 0; s < 2; ++s) {
        const int idx = s * NT + tid;   // 0..511
        const int r   = idx >> 4;       // 0..31
        const int c4  = idx & 15;       // 0..15 (k4)
        Af[c4][r] = emb4[(size_t)(tr0 + r) * 32 + h16 + c4];
        Bf[c4][r] = emb4[(size_t)(tc0 + r) * 32 + h16 + c4];
    }
    __syncthreads();

    // 2x2 micro-tile: rows (tr, tr+1), cols (tc, tc+16).
    const int tr = (tid >> 4) << 1;  // 0,2,...,30
    const int tc = tid & 15;         // 0..15

    float4 acc00 = {0,0,0,0}, acc01 = {0,0,0,0};
    float4 acc10 = {0,0,0,0}, acc11 = {0,0,0,0};
    float4 sa0   = {0,0,0,0}, sa1   = {0,0,0,0};
    float4 sb0   = {0,0,0,0}, sb1   = {0,0,0,0};
#pragma unroll
    for (int k4 = 0; k4 < 16; ++k4) {
        const float4 a0 = Af[k4][tr];
        const float4 a1 = Af[k4][tr + 1];
        const float4 b0 = Bf[k4][tc];
        const float4 b1 = Bf[k4][tc + 16];
        FMA4(acc00, a0, b0); FMA4(acc01, a0, b1);
        FMA4(acc10, a1, b0); FMA4(acc11, a1, b1);
        FMA4(sa0, a0, a0);   FMA4(sa1, a1, a1);
        FMA4(sb0, b0, b0);   FMA4(sb1, b1, b1);
    }

    const float qa0 = hsum4(sa0), qa1 = hsum4(sa1);
    const float qb0 = hsum4(sb0), qb1 = hsum4(sb1);
    float* outp = d2part + (size_t)h * BN * BN;
    const int r0 = tr0 + tr, c0 = tc0 + tc;
    outp[(size_t)r0 * BN + c0]            = qa0 + qb0 - 2.f * hsum4(acc00);
    outp[(size_t)r0 * BN + c0 + 16]       = qa0 + qb1 - 2.f * hsum4(acc01);
    outp[(size_t)(r0 + 1) * BN + c0]      = qa1 + qb0 - 2.f * hsum4(acc10);
    outp[(size_t)(r0 + 1) * BN + c0 + 16] = qa1 + qb1 - 2.f * hsum4(acc11);
}

// ---------------------------------------------------------------------------
// K2: per-anchor triplet accumulation + ticketed finalize. One block per i.
// ---------------------------------------------------------------------------
__global__ __launch_bounds__(NT) void triplet_kernel(
        const float* __restrict__ d2part,
        const int* __restrict__ labels,
        float* __restrict__ accum,   // [0]=sum, [1]=cnt, [2]=ticket(int)
        float* __restrict__ out) {
    const int i    = blockIdx.x;
    const int tid  = threadIdx.x;
    const int lane = tid & 63;
    const int wave = tid >> 6;

    __shared__ float drow[BN];
    __shared__ int   lab[BN];
    __shared__ int   pos_idx[BN];
    __shared__ int   npos_s;
    __shared__ float wsum[NW];
    __shared__ int   wcnt[NW];

    // Combine the two d2 halves, sqrt -> dist row (coalesced float2 loads).
    {
        const float2 va = *(const float2*)&d2part[(size_t)i * BN + 2 * tid];
        const float2 vb = *(const float2*)&d2part[(size_t)BN * BN +
                                                  (size_t)i * BN + 2 * tid];
        drow[2 * tid]     = sqrtf(fmaxf(va.x + vb.x, 1e-12f));
        drow[2 * tid + 1] = sqrtf(fmaxf(va.y + vb.y, 1e-12f));
    }
    lab[tid]       = labels[tid];
    lab[tid + 256] = labels[tid + 256];
    if (tid == 0) npos_s = 0;
    __syncthreads();

    const int li = lab[i];

    // Positives list (LDS atomic append).
    for (int j = tid; j < BN; j += NT) {
        if (lab[j] == li && j != i) {
            int p = atomicAdd(&npos_s, 1);
            pos_idx[p] = j;
        }
    }

    // Per-wave min over negatives + has_neg (barrier-free, redundant per wave).
    float mn = 1e30f;
    int   hn = 0;
    for (int k = lane; k < BN; k += 64) {
        if (lab[k] != li) { hn = 1; mn = fminf(mn, drow[k]); }
    }
#pragma unroll
    for (int off = 32; off > 0; off >>= 1) {
        mn = fminf(mn, __shfl_down(mn, off));
        hn |= __shfl_down(hn, off);
    }
    mn = __shfl(mn, 0);
    hn = __shfl(hn, 0);
    __syncthreads();  // npos_s / pos_idx ready

    // Positives round-robin over waves; wave-cooperative semi-hard max scan.
    float lsum = 0.f;
    int   lcnt = 0;
    const int npos = npos_s;
    if (hn) {
        for (int p = wave; p < npos; p += NW) {
            const float dap = drow[pos_idx[p]];
            const float hi  = dap + TMARGIN;
            float smax = -1e30f;
            for (int k = lane; k < BN; k += 64) {
                const float dan = drow[k];
                if (lab[k] != li && dan > dap && dan < hi)
                    smax = fmaxf(smax, dan);
            }
#pragma unroll
            for (int off = 32; off > 0; off >>= 1)
                smax = fmaxf(smax, __shfl_down(smax, off));
            if (lane == 0) {
                const float dneg = (smax > -1e29f) ? smax : mn;
                lsum += fmaxf(dap - dneg + TMARGIN, 0.f);
                lcnt += 1;
            }
        }
    }
    if (lane == 0) { wsum[wave] = lsum; wcnt[wave] = lcnt; }
    __syncthreads();

    if (tid == 0) {
        float s = 0.f;
        int   c = 0;
#pragma unroll
        for (int w = 0; w < NW; ++w) { s += wsum[w]; c += wcnt[w]; }
        atomicAdd(&accum[0], s);
        atomicAdd(&accum[1], (float)c);
        __threadfence();
        int t = atomicAdd((int*)(accum + 2), 1);
        if (t == (int)gridDim.x - 1) {
            const float total = atomicAdd(&accum[0], 0.f);
            const float cnt   = atomicAdd(&accum[1], 0.f);
            out[0] = (cnt > 0.f) ? (total / fmaxf(cnt, 1.f)) : 0.f;
        }
    }
}

extern "C" void kernel_launch(void* const* d_in, const int* in_sizes, int n_in,
                              void* d_out, int out_size, void* d_ws, size_t ws_size,
                              hipStream_t stream) {
    const float* emb    = (const float*)d_in[0];
    const int*   labels = (const int*)d_in[1];
    float*       out    = (float*)d_out;

    float* d2part = (float*)d_ws;                       // 2 * 512*512 floats = 2 MB
    float* accum  = d2part + 2 * (size_t)BN * BN;       // 3 words

    dist2_gemm_kernel<<<2 * 256, NT, 0, stream>>>(emb, d2part, accum);
    triplet_kernel<<<BN, NT, 0, stream>>>(d2part, labels, accum, out);
}